// Round 6
// baseline (300.858 us; speedup 1.0000x reference)
//
#include <hip/hip_runtime.h>
#include <math.h>

#define B_CONST 256
#define V_CONST 128000          // floats per row; 32000 float4
#define L_CONST 200
#define NBLOCKS 2048            // 8 blocks per row, exactly resident (8/CU)
#define F4_WAVE 1000            // 32 waves per row * 1000 f4 = 32000

// ws layout: int gt[256], int sub[256], int dist[256], unsigned ticket,
//            pad to 1024, float predicts[256]

__global__ __launch_bounds__(256) void prep_kernel(
    const float* __restrict__ scores,
    const int* __restrict__ labels,
    const int* __restrict__ seqs,
    int* __restrict__ gt,
    int* __restrict__ sub,
    int* __restrict__ dist,
    unsigned* __restrict__ ticket,
    float* __restrict__ predicts)
{
    const int b   = blockIdx.x;
    const int tid = threadIdx.x;
    __shared__ int s_seq[L_CONST];
    __shared__ int s_sub, s_dist;

    const float* row = scores + (size_t)b * V_CONST;
    if (tid == 0) { s_sub = 0; s_dist = 0; }
    if (tid < L_CONST) s_seq[tid] = seqs[b * L_CONST + tid];
    const float predict = row[labels[b]];
    __syncthreads();

    if (tid < L_CONST) {
        const int s = s_seq[tid];
        const float sv = row[s];            // gather early
        bool first = true;
        for (int j = 0; j < tid; ++j)
            if (s_seq[j] == s) { first = false; break; }
        if (first) {
            atomicAdd(&s_dist, 1);
            if (sv > predict) atomicAdd(&s_sub, 1);
        }
    }
    __syncthreads();

    if (tid == 0) {
        gt[b]       = 0;
        sub[b]      = s_sub;
        dist[b]     = s_dist;
        predicts[b] = predict;
        if (b == 0) *ticket = 0u;
    }
}

__global__ __launch_bounds__(256) void count_kernel(
    const float* __restrict__ scores,
    int* __restrict__ gt,
    const int* __restrict__ sub,
    const int* __restrict__ dist,
    unsigned* __restrict__ ticket,
    const float* __restrict__ predicts,
    float* __restrict__ out)
{
    const int tid  = threadIdx.x;
    const int lane = tid & 63;
    const int w    = tid >> 6;
    const int row  = blockIdx.x & 255;
    const int wslc = ((blockIdx.x >> 8) << 2) + w;      // 0..31, wave's slice of row

    const float4* p = (const float4*)(scores + (size_t)row * V_CONST) + wslc * F4_WAVE;

    // independent tail load issued up front (extra in-flight request)
    float4 tv;
    if (lane < 40) tv = p[960 + lane];
    const float predict = predicts[row];

    int cnt = 0;
    #pragma unroll 5
    for (int it = 0; it < 15; ++it) {
        float4 v = p[it * 64 + lane];
        cnt += (v.x > predict) + (v.y > predict) + (v.z > predict) + (v.w > predict);
    }
    if (lane < 40)
        cnt += (tv.x > predict) + (tv.y > predict) + (tv.z > predict) + (tv.w > predict);

    #pragma unroll
    for (int off = 32; off > 0; off >>= 1)
        cnt += __shfl_down(cnt, off, 64);
    if (lane == 0) atomicAdd(&gt[row], cnt);

    // ---- last-block finalize (ticket zeroed by prep dispatch) ----
    __shared__ int s_last;
    __shared__ float red[4];
    __syncthreads();                        // drains this block's vmem incl. atomics
    if (tid == 0) {
        __threadfence();                    // publish before ticket
        unsigned old = atomicAdd(ticket, 1u);
        s_last = (old == (unsigned)(NBLOCKS - 1));
    }
    __syncthreads();
    if (!s_last) return;

    __threadfence();                        // acquire side
    const int b = tid;                      // one row per thread
    const int gtv = atomicAdd(&gt[b], 0);   // coherent read of other blocks' adds
    const float rank  = (float)(gtv - sub[b]);
    const float valid = (float)(V_CONST - dist[b]);

    const float ks[5] = {1.0f, 5.0f, 10.0f, 20.0f, 50.0f};
    float vals[12];
    const float invlog = 1.0f / log2f(rank + 2.0f);
    #pragma unroll
    for (int i = 0; i < 5; ++i) {
        const float ind = (rank < ks[i]) ? 1.0f : 0.0f;
        vals[2 * i]     = ind * invlog;     // NDCG@k
        vals[2 * i + 1] = ind;              // Recall@k
    }
    vals[10] = 1.0f / (rank + 1.0f);        // MRR
    vals[11] = 1.0f - rank / valid;         // AUC-like

    for (int q = 0; q < 12; ++q) {
        float v = vals[q];
        #pragma unroll
        for (int off = 32; off > 0; off >>= 1)
            v += __shfl_down(v, off, 64);
        if ((b & 63) == 0) red[b >> 6] = v;
        __syncthreads();
        if (b == 0) out[q] = (red[0] + red[1] + red[2] + red[3]) * (1.0f / B_CONST);
        __syncthreads();
    }
    if (b == 0) out[12] = 0.0f;
}

extern "C" void kernel_launch(void* const* d_in, const int* in_sizes, int n_in,
                              void* d_out, int out_size, void* d_ws, size_t ws_size,
                              hipStream_t stream) {
    const float* scores = (const float*)d_in[0];
    const int*   labels = (const int*)d_in[1];
    const int*   seqs   = (const int*)d_in[2];
    float* out = (float*)d_out;
    int*   wsi = (int*)d_ws;

    int*      gt       = wsi;               // 256
    int*      sub      = wsi + 256;         // 256
    int*      dist     = wsi + 512;         // 256
    unsigned* ticket   = (unsigned*)(wsi + 768);
    float*    predicts = (float*)(wsi + 1024);  // 256

    prep_kernel<<<B_CONST, 256, 0, stream>>>(scores, labels, seqs,
                                             gt, sub, dist, ticket, predicts);
    count_kernel<<<NBLOCKS, 256, 0, stream>>>(scores, gt, sub, dist,
                                              ticket, predicts, out);
}